// Round 3
// baseline (128.927 us; speedup 1.0000x reference)
//
#include <hip/hip_runtime.h>
#include <stdint.h>
#include <string.h>
#include <algorithm>

#define NV 4096
#define NPOOL 1024
#define NB 8
#define KNB 16
#define INF_BITS 0x7F800000u

struct SIdx { unsigned short v[NPOOL]; };  // 2 KB by-value kernel arg

// ---------------- Threefry-2x32 (JAX-compatible, 20 rounds) ----------------
// Host copy — identical math to the device version that validated absmax=0.
static inline void tf2x32_host(uint32_t k0, uint32_t k1,
                               uint32_t c0, uint32_t c1,
                               uint32_t& o0, uint32_t& o1) {
  uint32_t ks0 = k0, ks1 = k1, ks2 = k0 ^ k1 ^ 0x1BD11BDAu;
  uint32_t x0 = c0 + ks0, x1 = c1 + ks1;
#define TFR(r) { x0 += x1; x1 = (x1 << (r)) | (x1 >> (32 - (r))); x1 ^= x0; }
  TFR(13) TFR(15) TFR(26) TFR(6)
  x0 += ks1; x1 += ks2 + 1u;
  TFR(17) TFR(29) TFR(16) TFR(24)
  x0 += ks2; x1 += ks0 + 2u;
  TFR(13) TFR(15) TFR(26) TFR(6)
  x0 += ks0; x1 += ks1 + 3u;
  TFR(17) TFR(29) TFR(16) TFR(24)
  x0 += ks1; x1 += ks2 + 4u;
  TFR(13) TFR(15) TFR(26) TFR(6)
  x0 += ks2; x1 += ks0 + 5u;
#undef TFR
  o0 = x0; o1 = x1;
}

// Host: replicate jax.random.permutation(key(42), 4096)[:1024]
// (partitionable threefry: split via tf(key,(0,i)); bits32 = o0^o1;
//  _shuffle = 2 rounds of stable sort_key_val by fresh 32-bit keys)
static void compute_sample_idx(SIdx& out) {
  static_assert(sizeof(SIdx) == 2048, "kernarg size");
  uint64_t arr[NV];
  uint16_t x[NV], tmp[NV];
  for (int i = 0; i < NV; ++i) x[i] = (uint16_t)i;
  uint32_t kh = 0u, kl = 42u;  // jax.random.key(42) -> (0, 42)
  for (int round = 0; round < 2; ++round) {
    uint32_t nkh, nkl, sh, sl, t0, t1;
    tf2x32_host(kh, kl, 0u, 0u, nkh, nkl);   // new key
    tf2x32_host(kh, kl, 0u, 1u, sh, sl);     // subkey
    kh = nkh; kl = nkl;
    for (int i = 0; i < NV; ++i) {
      tf2x32_host(sh, sl, 0u, (uint32_t)i, t0, t1);
      uint32_t bits = t0 ^ t1;
      arr[i] = ((uint64_t)bits << 32) | (uint32_t)i;  // (key, pos): unique -> stable
    }
    std::sort(arr, arr + NV);
    for (int i = 0; i < NV; ++i) tmp[i] = x[(uint32_t)(arr[i] & 0xffffffffu)];
    memcpy(x, tmp, sizeof(x));
  }
  for (int i = 0; i < NPOOL; ++i) out.v[i] = x[i];
}

// ---------------- K1: per sampled query, 16-NN (exact XLA-f32 distances) +
// fused feature gather/max + vertices_pool write. One wave per query.
__global__ __launch_bounds__(64) void knn_pool_kernel(
    const float* __restrict__ vertices, const float* __restrict__ fm,
    const SIdx sidx,
    float* __restrict__ outV, float* __restrict__ outF) {
  __shared__ uint32_t distb[NV];
  const int lane = threadIdx.x;
  const int q = blockIdx.x;        // 0..8191
  const int b = q >> 10;
  const int i = q & 1023;
  const int n = (int)sidx.v[i];

  const float* vb = vertices + (size_t)b * NV * 3;
  const float qx = vb[n * 3 + 0], qy = vb[n * 3 + 1], qz = vb[n * 3 + 2];
  // quadratic[n]: plain mul/add (XLA reduce of squares)
  const float qn = __fadd_rn(__fadd_rn(__fmul_rn(qx, qx), __fmul_rn(qy, qy)),
                             __fmul_rn(qz, qz));

  // distances: each lane owns LDS slots m = lane + 64*t (private region)
  for (int t = 0; t < 64; ++t) {
    const int m = (t << 6) + lane;
    const float cx = vb[m * 3 + 0], cy = vb[m * 3 + 1], cz = vb[m * 3 + 2];
    // Eigen gemm: acc = fma(a_k, b_k, acc), acc0 = round(a0*b0)
    const float inner = __fmaf_rn(cz, qz, __fmaf_rn(cy, qy, __fmul_rn(cx, qx)));
    const float qm = __fadd_rn(__fadd_rn(__fmul_rn(cx, cx), __fmul_rn(cy, cy)),
                               __fmul_rn(cz, cz));
    // distance = (-2*inner + quadratic[m]) + quadratic[n]
    const float d = __fadd_rn(__fadd_rn(__fmul_rn(-2.0f, inner), qm), qn);
    distb[m] = (m == n) ? INF_BITS : __float_as_uint(d);  // positive floats: uint order
  }
  __syncthreads();

  const float* fmb = fm + (size_t)b * NV * 256;
  float a0 = -INFINITY, a1 = -INFINITY, a2 = -INFINITY, a3 = -INFINITY;

  for (int s = 0; s < KNB; ++s) {
    // per-lane min over its private 64 entries (ascending m => smallest idx on tie)
    uint32_t best = 0xFFFFFFFFu;
    int bi = -1;
    for (int t = 0; t < 64; ++t) {
      const int m = (t << 6) + lane;
      const uint32_t v = distb[m];
      if (v < best) { best = v; bi = m; }
    }
    // wave reduce with (dist, index) lexicographic tie-break
    for (int off = 32; off > 0; off >>= 1) {
      const uint32_t ov = (uint32_t)__shfl_down((int)best, off);
      const int oi = __shfl_down(bi, off);
      if (ov < best || (ov == best && (uint32_t)oi < (uint32_t)bi)) { best = ov; bi = oi; }
    }
    const int w = __shfl(bi, 0);
    if ((w & 63) == lane) distb[w] = INF_BITS;  // owner lane marks its own slot
    __syncthreads();

    // fused gather + max of winner's feature row (coalesced)
    const float* row = fmb + (size_t)w * 256;
    a0 = fmaxf(a0, row[lane]);
    a1 = fmaxf(a1, row[64 + lane]);
    a2 = fmaxf(a2, row[128 + lane]);
    a3 = fmaxf(a3, row[192 + lane]);
  }

  float* of = outF + ((size_t)b * NPOOL + i) * 256;
  of[lane] = a0;
  of[64 + lane] = a1;
  of[128 + lane] = a2;
  of[192 + lane] = a3;

  if (lane == 0) {
    float* ov = outV + ((size_t)b * NPOOL + i) * 3;
    ov[0] = qx; ov[1] = qy; ov[2] = qz;
  }
}

extern "C" void kernel_launch(void* const* d_in, const int* in_sizes, int n_in,
                              void* d_out, int out_size, void* d_ws, size_t ws_size,
                              hipStream_t stream) {
  const float* vertices = (const float*)d_in[0];
  const float* fm = (const float*)d_in[1];
  float* out = (float*)d_out;
  float* outV = out;                      // (8, 1024, 3)
  float* outF = out + NB * NPOOL * 3;     // (8, 1024, 256)

  SIdx sidx;
  compute_sample_idx(sidx);               // pure host constant of key(42)

  knn_pool_kernel<<<NB * NPOOL, 64, 0, stream>>>(vertices, fm, sidx, outV, outF);
}